// Round 9
// baseline (294.424 us; speedup 1.0000x reference)
//
#include <hip/hip_runtime.h>

#define N_EDGES   1250000
#define N_ENT     100000
#define N_USR     100000
#define N_ITM     50000
#define CH        64
#define CAP       48        // bucket capacity; deg ~ Poisson(12.5), P(>48) ~ 1e-14

#define ITEM_TILES ((N_ITM + 63) / 64)   // 782
#define USER_TILES ((N_USR + 63) / 64)   // 1563
#define TOT_TILES  (ITEM_TILES + USER_TILES)   // 2345

#define EPT 2                                     // R2-proven: 2 edges/thread
#define SCAT_BLKS ((N_EDGES + 256*EPT - 1) / (256*EPT))   // 2442 >= TOT_TILES

// round-to-nearest-even fp32 -> bf16
__device__ __forceinline__ unsigned short bf16_rne(float f) {
    unsigned u = __float_as_uint(f);
    unsigned r = u + 0x7FFFu + ((u >> 16) & 1u);
    return (unsigned short)(r >> 16);
}

// ============================================================================
// Dispatch 2: fc-bucket scatter (2 edges/thread) + hoisted fp32->bf16
// conversion (R8-proven) + LDS-free GEMM tail.
// R9 experiment: cursor stride `cstride` (16 => one cursor per 64B line).
// Theory: 1.25M memory-side atomics over 6250 dense lines = ~200 RMW/line,
// serialized per line => the ~125us scatter floor. Padding isolates lines.
// Softmax row-sum == 1 exactly -> reference's score GEMMs are dead code;
// user/item agg = 2*(interact_mat @ aspect_emb).
// ============================================================================
__global__ __launch_bounds__(256, 4) void scatter_gemm_kernel(
    const int*   __restrict__ edge_index,
    const int*   __restrict__ edge_type,
    const float* __restrict__ entity_emb,
    const float* __restrict__ aspect_emb,
    const float* __restrict__ ia_mat,
    const float* __restrict__ ua_mat,
    unsigned* __restrict__ cursor,
    unsigned* __restrict__ keys,
    unsigned short* __restrict__ ent16,     // nullptr => skip conversion
    int cstride,
    float* __restrict__ out_item,
    float* __restrict__ out_user)
{
    const int tid = blockIdx.x * 256 + threadIdx.x;
    const int nth = SCAT_BLKS * 256;

    // ---- conversion loads issued FIRST (fly during the atomic round-trips) --
    bool  cvalid[3];
    float4 cv[3];
    {
        const float4* src = (const float4*)entity_emb;
        #pragma unroll
        for (int k = 0; k < 3; ++k) {
            int g = tid + k * nth;
            cvalid[k] = (ent16 != nullptr) && (g < N_ENT * 16);
            cv[k] = cvalid[k] ? src[g] : make_float4(0.f, 0.f, 0.f, 0.f);
        }
    }

    // ---- Phase A: scatter two edges; independent atomics overlap -----------
    {
        const int eA = blockIdx.x * (256 * EPT) + threadIdx.x;
        const int eB = eA + 256;
        const bool vA = (eA < N_EDGES);
        const bool vB = (eB < N_EDGES);
        const int la = vA ? eA : 0;
        const int lb = vB ? eB : 0;

        int headA = __builtin_nontemporal_load(&edge_index[la]);
        int headB = __builtin_nontemporal_load(&edge_index[lb]);
        int tailA = __builtin_nontemporal_load(&edge_index[N_EDGES + la]);
        int tailB = __builtin_nontemporal_load(&edge_index[N_EDGES + lb]);
        int relA  = __builtin_nontemporal_load(&edge_type[la]) - 2;
        int relB  = __builtin_nontemporal_load(&edge_type[lb]) - 2;

        unsigned posA = 0xFFFFFFFFu, posB = 0xFFFFFFFFu;
        if (vA) posA = atomicAdd(&cursor[(size_t)headA * cstride], 1u);
        if (vB) posB = atomicAdd(&cursor[(size_t)headB * cstride], 1u);

        if (vA && posA < CAP)
            keys[(unsigned)headA * CAP + posA] =
                (unsigned)tailA | ((unsigned)relA << 20);
        if (vB && posB < CAP)
            keys[(unsigned)headB * CAP + posB] =
                (unsigned)tailB | ((unsigned)relB << 20);
    }

    // ---- conversion stores (data arrived during the atomic phase) ----------
    {
        ushort4* dst = (ushort4*)ent16;
        #pragma unroll
        for (int k = 0; k < 3; ++k) {
            if (cvalid[k]) {
                int g = tid + k * nth;
                ushort4 o;
                o.x = bf16_rne(cv[k].x); o.y = bf16_rne(cv[k].y);
                o.z = bf16_rne(cv[k].z); o.w = bf16_rne(cv[k].w);
                dst[g] = o;
            }
        }
    }

    // ---- Phase B: one 64x64 GEMM tile per early block (LDS-free) -----------
    int tile = blockIdx.x;
    if (tile >= TOT_TILES) return;

    const float* M; float* out; int N, tt;
    if (tile < ITEM_TILES) { M = ia_mat; out = out_item; N = N_ITM; tt = tile; }
    else                   { M = ua_mat; out = out_user; N = N_USR; tt = tile - ITEM_TILES; }
    const int row0 = tt * 64;

    const int t  = threadIdx.x;
    const int ci = t & 15;          // output col float4-group; coalesced A reads
    const int r0 = (t >> 4) * 4;    // 4 output rows

    const float4* A4 = (const float4*)aspect_emb;   // 16 KB, L1-resident
    const float4* M4 = (const float4*)M;

    int r[4];
    #pragma unroll
    for (int j = 0; j < 4; ++j) {
        int rr = row0 + r0 + j;
        r[j] = (rr < N) ? rr : (N - 1);     // clamp reads; stores guarded below
    }

    float4 acc[4];
    #pragma unroll
    for (int j = 0; j < 4; ++j) acc[j] = make_float4(0.f, 0.f, 0.f, 0.f);

    #pragma unroll 4
    for (int k4 = 0; k4 < 16; ++k4) {
        float4 a0 = A4[(k4 * 4 + 0) * 16 + ci];
        float4 a1 = A4[(k4 * 4 + 1) * 16 + ci];
        float4 a2 = A4[(k4 * 4 + 2) * 16 + ci];
        float4 a3 = A4[(k4 * 4 + 3) * 16 + ci];
        #pragma unroll
        for (int j = 0; j < 4; ++j) {
            float4 mv = M4[(size_t)r[j] * 16 + k4];
            acc[j].x += mv.x * a0.x + mv.y * a1.x + mv.z * a2.x + mv.w * a3.x;
            acc[j].y += mv.x * a0.y + mv.y * a1.y + mv.z * a2.y + mv.w * a3.y;
            acc[j].z += mv.x * a0.z + mv.y * a1.z + mv.z * a2.z + mv.w * a3.z;
            acc[j].w += mv.x * a0.w + mv.y * a1.w + mv.z * a2.w + mv.w * a3.w;
        }
    }

    float4* out4 = (float4*)out;
    #pragma unroll
    for (int j = 0; j < 4; ++j) {
        int rr = row0 + r0 + j;
        if (rr < N) {
            float4 v = acc[j];
            v.x *= 2.f; v.y *= 2.f; v.z *= 2.f; v.w *= 2.f;
            out4[(size_t)rr * 16 + ci] = v;
        }
    }
}

// ============================================================================
// Dispatch 3 (tier-1/2): bf16 segmented reduce, ONE entity per wave,
// 8 slots x 8 q-lanes (R8 config, unchanged this round for single-variable
// discipline). Per lane-edge: one 16B gather (8 bf16 ch); fp32 weight (L1)
// + fp32 accumulate.
// ============================================================================
__global__ __launch_bounds__(256, 8) void reduce_bf16_kernel(
    const unsigned short* __restrict__ ent16,
    const float* __restrict__ weight,
    const unsigned* __restrict__ cursor,
    const unsigned* __restrict__ keys,
    int cstride,
    float* __restrict__ out_ent)
{
    const int gtid = blockIdx.x * 256 + threadIdx.x;
    const int ent  = gtid >> 6;                 // grid sized so ent < N_ENT
    const int lane = threadIdx.x & 63;
    const int slot = lane >> 3;                 // 0..7
    const int q    = lane & 7;                  // 8-channel group index

    unsigned c = cursor[(size_t)ent * cstride];
    if (c > CAP) c = CAP;
    const unsigned* bucket = keys + (unsigned)ent * CAP;

    // number of keys this slot handles: 0..6
    const int nk = ((int)c > slot) ? (int)((c - (unsigned)slot + 7u) >> 3) : 0;

    unsigned kr[6];
    #pragma unroll
    for (int i = 0; i < 6; ++i)
        kr[i] = (i < nk) ? __builtin_nontemporal_load(&bucket[slot + 8 * i]) : 0u;

    const uint4*  e16 = (const uint4*)ent16;    // row = 8 x uint4 (8 bf16 ch each)
    const float4* w4  = (const float4*)weight;

    float4 acc0 = make_float4(0.f, 0.f, 0.f, 0.f);
    float4 acc1 = make_float4(0.f, 0.f, 0.f, 0.f);

    #pragma unroll
    for (int i = 0; i < 6; ++i) {
        if (i < nk) {
            unsigned key  = kr[i];
            unsigned tail = key & 0xFFFFFu;
            unsigned rel  = key >> 20;
            uint4 ev = e16[(size_t)tail * 8 + q];
            const float4* wp = w4 + rel * 16 + q * 2;
            float4 w0 = wp[0], w1 = wp[1];
            float e0 = __uint_as_float(ev.x << 16);
            float e1 = __uint_as_float(ev.x & 0xFFFF0000u);
            float e2 = __uint_as_float(ev.y << 16);
            float e3 = __uint_as_float(ev.y & 0xFFFF0000u);
            float e4 = __uint_as_float(ev.z << 16);
            float e5 = __uint_as_float(ev.z & 0xFFFF0000u);
            float e6 = __uint_as_float(ev.w << 16);
            float e7 = __uint_as_float(ev.w & 0xFFFF0000u);
            acc0.x += e0 * w0.x; acc0.y += e1 * w0.y;
            acc0.z += e2 * w0.z; acc0.w += e3 * w0.w;
            acc1.x += e4 * w1.x; acc1.y += e5 * w1.y;
            acc1.z += e6 * w1.z; acc1.w += e7 * w1.w;
        }
    }

    // cross-slot reduce: fold slot bits (8, 16, 32)
    #pragma unroll
    for (int off = 8; off <= 32; off <<= 1) {
        acc0.x += __shfl_xor(acc0.x, off); acc0.y += __shfl_xor(acc0.y, off);
        acc0.z += __shfl_xor(acc0.z, off); acc0.w += __shfl_xor(acc0.w, off);
        acc1.x += __shfl_xor(acc1.x, off); acc1.y += __shfl_xor(acc1.y, off);
        acc1.z += __shfl_xor(acc1.z, off); acc1.w += __shfl_xor(acc1.w, off);
    }

    if (slot == 0) {
        float inv = 1.0f / fmaxf((float)c, 1.0f);
        acc0.x *= inv; acc0.y *= inv; acc0.z *= inv; acc0.w *= inv;
        acc1.x *= inv; acc1.y *= inv; acc1.z *= inv; acc1.w *= inv;
        float4* o = (float4*)out_ent + (size_t)ent * 16 + q * 2;
        o[0] = acc0;
        o[1] = acc1;
    }
}

// ============================================================================
// Dispatch 3 (tier-3, R6-proven): fp32 segmented reduce, 2 entities/wave.
// ============================================================================
__global__ __launch_bounds__(256, 4) void reduce_kernel(
    const float* __restrict__ entity_emb,
    const float* __restrict__ weight,
    const unsigned* __restrict__ cursor,
    const unsigned* __restrict__ keys,
    float* __restrict__ out_ent)
{
    const int gtid = blockIdx.x * 256 + threadIdx.x;
    const int wave = gtid >> 6;
    const int lane = threadIdx.x & 63;
    const int half = lane >> 5;
    const int l32  = lane & 31;
    const int slot = l32 >> 3;
    const int q    = lane & 7;

    const int ent = wave * 2 + half;

    unsigned c = cursor[ent];
    if (c > CAP) c = CAP;
    const unsigned* bucket = keys + (unsigned)ent * CAP;

    const int nk = ((int)c > slot) ? (int)((c - (unsigned)slot + 3u) >> 2) : 0;

    unsigned kr[12];
    #pragma unroll
    for (int i = 0; i < 12; ++i)
        kr[i] = (i < nk) ? __builtin_nontemporal_load(&bucket[slot + 4 * i]) : 0u;

    const float4* emb4 = (const float4*)entity_emb;
    const float4* w4   = (const float4*)weight;

    float4 acc0 = make_float4(0.f, 0.f, 0.f, 0.f);
    float4 acc1 = make_float4(0.f, 0.f, 0.f, 0.f);

    #pragma unroll
    for (int i = 0; i < 12; ++i) {
        if (i < nk) {
            unsigned key  = kr[i];
            unsigned tail = key & 0xFFFFFu;
            unsigned rel  = key >> 20;
            const float4* ep = emb4 + (size_t)tail * 16 + q * 2;
            const float4* wp = w4 + rel * 16 + q * 2;
            float4 e0 = ep[0], e1 = ep[1];
            float4 w0 = wp[0], w1 = wp[1];
            acc0.x += e0.x * w0.x; acc0.y += e0.y * w0.y;
            acc0.z += e0.z * w0.z; acc0.w += e0.w * w0.w;
            acc1.x += e1.x * w1.x; acc1.y += e1.y * w1.y;
            acc1.z += e1.z * w1.z; acc1.w += e1.w * w1.w;
        }
    }

    #pragma unroll
    for (int off = 8; off <= 16; off <<= 1) {
        acc0.x += __shfl_xor(acc0.x, off); acc0.y += __shfl_xor(acc0.y, off);
        acc0.z += __shfl_xor(acc0.z, off); acc0.w += __shfl_xor(acc0.w, off);
        acc1.x += __shfl_xor(acc1.x, off); acc1.y += __shfl_xor(acc1.y, off);
        acc1.z += __shfl_xor(acc1.z, off); acc1.w += __shfl_xor(acc1.w, off);
    }

    if (slot == 0) {
        float inv = 1.0f / fmaxf((float)c, 1.0f);
        acc0.x *= inv; acc0.y *= inv; acc0.z *= inv; acc0.w *= inv;
        acc1.x *= inv; acc1.y *= inv; acc1.z *= inv; acc1.w *= inv;
        float4* o = (float4*)out_ent + (size_t)ent * 16 + q * 2;
        o[0] = acc0;
        o[1] = acc1;
    }
}

// ============================================================================
// Fallback (ws too small): R1-proven atomic path.
// ============================================================================
__global__ __launch_bounds__(256) void scatter_kernel(
    const float* __restrict__ entity_emb,
    const int* __restrict__ edge_index, const int* __restrict__ edge_type,
    const float* __restrict__ weight,
    float* __restrict__ ent_sum, float* __restrict__ cnt)
{
    int idx = blockIdx.x * 256 + threadIdx.x;
    int e = idx >> 4;
    int q = idx & 15;
    if (e >= N_EDGES) return;
    int head = edge_index[e];
    int tail = edge_index[N_EDGES + e];
    int rel  = edge_type[e] - 2;
    const float4* emb4 = (const float4*)entity_emb;
    const float4* w4   = (const float4*)weight;
    float4 ev = emb4[(size_t)tail * 16 + q];
    float4 wv = w4[rel * 16 + q];
    float* dst = ent_sum + (size_t)head * 64 + q * 4;
    atomicAdd(dst + 0, ev.x * wv.x);
    atomicAdd(dst + 1, ev.y * wv.y);
    atomicAdd(dst + 2, ev.z * wv.z);
    atomicAdd(dst + 3, ev.w * wv.w);
    if (q == 0) atomicAdd(&cnt[head], 1.0f);
}

__global__ __launch_bounds__(256) void divide_kernel(
    float* __restrict__ ent, const float* __restrict__ cnt)
{
    int idx = blockIdx.x * 256 + threadIdx.x;
    if (idx >= N_ENT * 16) return;
    int row = idx >> 4;
    float inv = 1.0f / fmaxf(cnt[row], 1.0f);
    float4* p = (float4*)ent;
    float4 v = p[idx];
    v.x *= inv; v.y *= inv; v.z *= inv; v.w *= inv;
    p[idx] = v;
}

__global__ __launch_bounds__(256) void gemm_fallback_kernel(
    const float* __restrict__ ia, const float* __restrict__ ua,
    const float* __restrict__ A,
    float* __restrict__ out_item, float* __restrict__ out_user)
{
    int tile = blockIdx.x;
    const float* M; float* out; int N, tt;
    if (tile < ITEM_TILES) { M = ia; out = out_item; N = N_ITM; tt = tile; }
    else                   { M = ua; out = out_user; N = N_USR; tt = tile - ITEM_TILES; }
    const int row0 = tt * 64;
    const int t  = threadIdx.x;
    const int ci = t & 15;
    const int r0 = (t >> 4) * 4;
    const float4* A4 = (const float4*)A;
    const float4* M4 = (const float4*)M;
    int r[4];
    #pragma unroll
    for (int j = 0; j < 4; ++j) {
        int rr = row0 + r0 + j;
        r[j] = (rr < N) ? rr : (N - 1);
    }
    float4 acc[4];
    #pragma unroll
    for (int j = 0; j < 4; ++j) acc[j] = make_float4(0.f, 0.f, 0.f, 0.f);
    #pragma unroll 4
    for (int k4 = 0; k4 < 16; ++k4) {
        float4 a0 = A4[(k4 * 4 + 0) * 16 + ci];
        float4 a1 = A4[(k4 * 4 + 1) * 16 + ci];
        float4 a2 = A4[(k4 * 4 + 2) * 16 + ci];
        float4 a3 = A4[(k4 * 4 + 3) * 16 + ci];
        #pragma unroll
        for (int j = 0; j < 4; ++j) {
            float4 mv = M4[(size_t)r[j] * 16 + k4];
            acc[j].x += mv.x * a0.x + mv.y * a1.x + mv.z * a2.x + mv.w * a3.x;
            acc[j].y += mv.x * a0.y + mv.y * a1.y + mv.z * a2.y + mv.w * a3.y;
            acc[j].z += mv.x * a0.z + mv.y * a1.z + mv.z * a2.z + mv.w * a3.z;
            acc[j].w += mv.x * a0.w + mv.y * a1.w + mv.z * a2.w + mv.w * a3.w;
        }
    }
    float4* out4 = (float4*)out;
    #pragma unroll
    for (int j = 0; j < 4; ++j) {
        int rr = row0 + r0 + j;
        if (rr < N) {
            float4 v = acc[j];
            v.x *= 2.f; v.y *= 2.f; v.z *= 2.f; v.w *= 2.f;
            out4[(size_t)rr * 16 + ci] = v;
        }
    }
}

// ============================================================================
extern "C" void kernel_launch(void* const* d_in, const int* in_sizes, int n_in,
                              void* d_out, int out_size, void* d_ws, size_t ws_size,
                              hipStream_t stream) {
    const float* entity_emb = (const float*)d_in[0];
    const float* aspect_emb = (const float*)d_in[3];
    const int*   edge_index = (const int*)d_in[4];
    const int*   edge_type  = (const int*)d_in[5];
    const float* ua_mat     = (const float*)d_in[6];
    const float* ia_mat     = (const float*)d_in[7];
    const float* weight     = (const float*)d_in[8];

    float* out_item = (float*)d_out;
    float* out_ent  = out_item + (size_t)N_ITM * CH;
    float* out_user = out_ent  + (size_t)N_ENT * CH;

    size_t need_fc  = ((size_t)N_ENT + (size_t)N_ENT * CAP) * 4;          // ~19.6 MB
    size_t need_bf  = need_fc + (size_t)N_ENT * CH * 2;                   // ~32.4 MB
    size_t need_pad = ((size_t)N_ENT * 16 + (size_t)N_ENT * CAP) * 4
                      + (size_t)N_ENT * CH * 2;                           // ~38.4 MB

    if (ws_size >= need_bf) {
        // tier-1 (padded cursor, 64B line isolation) or tier-2 (R8 exact)
        const int cstride = (ws_size >= need_pad) ? 16 : 1;
        unsigned* cursor = (unsigned*)d_ws;
        unsigned* keys   = cursor + (size_t)N_ENT * cstride;
        unsigned short* ent16 = (unsigned short*)(keys + (size_t)N_ENT * CAP);

        (void)hipMemsetAsync(cursor, 0, (size_t)N_ENT * cstride * 4, stream);
        scatter_gemm_kernel<<<SCAT_BLKS, 256, 0, stream>>>(
            edge_index, edge_type, entity_emb, aspect_emb, ia_mat, ua_mat,
            cursor, keys, ent16, cstride, out_item, out_user);
        // 1 entity/wave: N_ENT waves = 25000 blocks
        reduce_bf16_kernel<<<(N_ENT * 64) / 256, 256, 0, stream>>>(
            ent16, weight, cursor, keys, cstride, out_ent);
    } else if (ws_size >= need_fc) {
        unsigned* cursor = (unsigned*)d_ws;
        unsigned* keys   = cursor + N_ENT;

        (void)hipMemsetAsync(cursor, 0, (size_t)N_ENT * 4, stream);
        scatter_gemm_kernel<<<SCAT_BLKS, 256, 0, stream>>>(
            edge_index, edge_type, entity_emb, aspect_emb, ia_mat, ua_mat,
            cursor, keys, nullptr, 1, out_item, out_user);
        reduce_kernel<<<(N_ENT / 2) * 64 / 256, 256, 0, stream>>>(
            entity_emb, weight, cursor, keys, out_ent);
    } else {
        float* cnt = (float*)d_ws;
        (void)hipMemsetAsync(out_ent, 0, (size_t)N_ENT * CH * sizeof(float), stream);
        (void)hipMemsetAsync(cnt, 0, (size_t)N_ENT * sizeof(float), stream);
        scatter_kernel<<<(N_EDGES * 16 + 255) / 256, 256, 0, stream>>>(
            entity_emb, edge_index, edge_type, weight, out_ent, cnt);
        divide_kernel<<<(N_ENT * 16 + 255) / 256, 256, 0, stream>>>(out_ent, cnt);
        gemm_fallback_kernel<<<TOT_TILES, 256, 0, stream>>>(
            ia_mat, ua_mat, aspect_emb, out_item, out_user);
    }
}

// Round 10
// 281.486 us; speedup vs baseline: 1.0460x; 1.0460x over previous
//
#include <hip/hip_runtime.h>

#define N_EDGES   1250000
#define N_ENT     100000
#define N_USR     100000
#define N_ITM     50000
#define CH        64
#define CAP       48        // bucket capacity; deg ~ Poisson(12.5), P(>48) ~ 1e-14

#define ITEM_TILES ((N_ITM + 63) / 64)   // 782
#define USER_TILES ((N_USR + 63) / 64)   // 1563
#define TOT_TILES  (ITEM_TILES + USER_TILES)   // 2345

#define EPT 2                                     // R2-proven: 2 edges/thread
#define SCAT_BLKS ((N_EDGES + 256*EPT - 1) / (256*EPT))   // 2442 >= TOT_TILES

// round-to-nearest-even fp32 -> bf16
__device__ __forceinline__ unsigned short bf16_rne(float f) {
    unsigned u = __float_as_uint(f);
    unsigned r = u + 0x7FFFu + ((u >> 16) & 1u);
    return (unsigned short)(r >> 16);
}

// ============================================================================
// Dispatch 2: fc-bucket scatter + bf16 conversion + GEMM tail.
// R10 experiment: ISSUE atomics early, WAIT late. Order per block:
//   conv loads -> edge loads + atomicAdd issue -> conv stores -> FULL GEMM
//   -> key writes (first use of atomic returns => s_waitcnt lands here).
// The atomic round-trip hides under ~25us of GEMM work (same hazard class
// R8 fixed for conversion loads: +17us there). If null, the scatter is
// throughput-bound at the memory-side service floor, not latency-bound.
// Softmax row-sum == 1 exactly -> reference's score GEMMs are dead code;
// user/item agg = 2*(interact_mat @ aspect_emb).
// ============================================================================
__global__ __launch_bounds__(256, 4) void scatter_gemm_kernel(
    const int*   __restrict__ edge_index,
    const int*   __restrict__ edge_type,
    const float* __restrict__ entity_emb,
    const float* __restrict__ aspect_emb,
    const float* __restrict__ ia_mat,
    const float* __restrict__ ua_mat,
    unsigned* __restrict__ cursor,
    unsigned* __restrict__ keys,
    unsigned short* __restrict__ ent16,     // nullptr => skip conversion
    int cstride,
    float* __restrict__ out_item,
    float* __restrict__ out_user)
{
    const int tid = blockIdx.x * 256 + threadIdx.x;
    const int nth = SCAT_BLKS * 256;

    // ---- conversion loads issued FIRST (R8-proven) --------------------------
    bool  cvalid[3];
    float4 cv[3];
    {
        const float4* src = (const float4*)entity_emb;
        #pragma unroll
        for (int k = 0; k < 3; ++k) {
            int g = tid + k * nth;
            cvalid[k] = (ent16 != nullptr) && (g < N_ENT * 16);
            cv[k] = cvalid[k] ? src[g] : make_float4(0.f, 0.f, 0.f, 0.f);
        }
    }

    // ---- edge loads + atomic ISSUE (returns not consumed until the end) ----
    const int eA = blockIdx.x * (256 * EPT) + threadIdx.x;
    const int eB = eA + 256;
    const bool vA = (eA < N_EDGES);
    const bool vB = (eB < N_EDGES);
    {
        const int la = vA ? eA : 0;
        const int lb = vB ? eB : 0;

        int headA_ = __builtin_nontemporal_load(&edge_index[la]);
        int headB_ = __builtin_nontemporal_load(&edge_index[lb]);
        int tailA  = __builtin_nontemporal_load(&edge_index[N_EDGES + la]);
        int tailB  = __builtin_nontemporal_load(&edge_index[N_EDGES + lb]);
        int relA   = __builtin_nontemporal_load(&edge_type[la]) - 2;
        int relB   = __builtin_nontemporal_load(&edge_type[lb]) - 2;

        // fallthrough state carried across the GEMM (packed to minimize VGPR)
        extern __shared__ char _dummy[];   // (unused; keeps compiler honest)
        (void)_dummy;

        unsigned keyA = (unsigned)tailA | ((unsigned)relA << 20);
        unsigned keyB = (unsigned)tailB | ((unsigned)relB << 20);
        unsigned posA = 0xFFFFFFFFu, posB = 0xFFFFFFFFu;
        if (vA) posA = atomicAdd(&cursor[(size_t)headA_ * cstride], 1u);
        if (vB) posB = atomicAdd(&cursor[(size_t)headB_ * cstride], 1u);

        // ---- conversion stores (only need conv loads; independent of atomics)
        {
            ushort4* dst = (ushort4*)ent16;
            #pragma unroll
            for (int k = 0; k < 3; ++k) {
                if (cvalid[k]) {
                    int g = tid + k * nth;
                    ushort4 o;
                    o.x = bf16_rne(cv[k].x); o.y = bf16_rne(cv[k].y);
                    o.z = bf16_rne(cv[k].z); o.w = bf16_rne(cv[k].w);
                    dst[g] = o;
                }
            }
        }

        // ---- GEMM tile (independent work; atomic returns still in flight) --
        int tile = blockIdx.x;
        if (tile < TOT_TILES) {
            const float* M; float* out; int N, tt;
            if (tile < ITEM_TILES) { M = ia_mat; out = out_item; N = N_ITM; tt = tile; }
            else                   { M = ua_mat; out = out_user; N = N_USR; tt = tile - ITEM_TILES; }
            const int row0 = tt * 64;

            const int t  = threadIdx.x;
            const int ci = t & 15;          // output col float4-group
            const int r0 = (t >> 4) * 4;    // 4 output rows

            const float4* A4 = (const float4*)aspect_emb;   // 16 KB, L1-resident
            const float4* M4 = (const float4*)M;

            int r[4];
            #pragma unroll
            for (int j = 0; j < 4; ++j) {
                int rr = row0 + r0 + j;
                r[j] = (rr < N) ? rr : (N - 1);
            }

            float4 acc[4];
            #pragma unroll
            for (int j = 0; j < 4; ++j) acc[j] = make_float4(0.f, 0.f, 0.f, 0.f);

            #pragma unroll 4
            for (int k4 = 0; k4 < 16; ++k4) {
                float4 a0 = A4[(k4 * 4 + 0) * 16 + ci];
                float4 a1 = A4[(k4 * 4 + 1) * 16 + ci];
                float4 a2 = A4[(k4 * 4 + 2) * 16 + ci];
                float4 a3 = A4[(k4 * 4 + 3) * 16 + ci];
                #pragma unroll
                for (int j = 0; j < 4; ++j) {
                    float4 mv = M4[(size_t)r[j] * 16 + k4];
                    acc[j].x += mv.x * a0.x + mv.y * a1.x + mv.z * a2.x + mv.w * a3.x;
                    acc[j].y += mv.x * a0.y + mv.y * a1.y + mv.z * a2.y + mv.w * a3.y;
                    acc[j].z += mv.x * a0.z + mv.y * a1.z + mv.z * a2.z + mv.w * a3.z;
                    acc[j].w += mv.x * a0.w + mv.y * a1.w + mv.z * a2.w + mv.w * a3.w;
                }
            }

            float4* out4 = (float4*)out;
            #pragma unroll
            for (int j = 0; j < 4; ++j) {
                int rr = row0 + r0 + j;
                if (rr < N) {
                    float4 v = acc[j];
                    v.x *= 2.f; v.y *= 2.f; v.z *= 2.f; v.w *= 2.f;
                    out4[(size_t)rr * 16 + ci] = v;
                }
            }
        }

        // ---- key writes LAST: first consumption of posA/posB ---------------
        if (vA && posA < CAP)
            keys[(unsigned)headA_ * CAP + posA] = keyA;
        if (vB && posB < CAP)
            keys[(unsigned)headB_ * CAP + posB] = keyB;
    }
}

// ============================================================================
// Dispatch 3 (tier-1/2): bf16 segmented reduce, ONE entity per wave,
// 8 slots x 8 q-lanes, keys prefetched. Per lane-edge: one 16B gather
// (8 bf16 ch); fp32 weight (L1) + fp32 accumulate. Unchanged from R8/R9.
// ============================================================================
__global__ __launch_bounds__(256, 8) void reduce_bf16_kernel(
    const unsigned short* __restrict__ ent16,
    const float* __restrict__ weight,
    const unsigned* __restrict__ cursor,
    const unsigned* __restrict__ keys,
    int cstride,
    float* __restrict__ out_ent)
{
    const int gtid = blockIdx.x * 256 + threadIdx.x;
    const int ent  = gtid >> 6;                 // grid sized so ent < N_ENT
    const int lane = threadIdx.x & 63;
    const int slot = lane >> 3;                 // 0..7
    const int q    = lane & 7;                  // 8-channel group index

    unsigned c = cursor[(size_t)ent * cstride];
    if (c > CAP) c = CAP;
    const unsigned* bucket = keys + (unsigned)ent * CAP;

    // number of keys this slot handles: 0..6
    const int nk = ((int)c > slot) ? (int)((c - (unsigned)slot + 7u) >> 3) : 0;

    unsigned kr[6];
    #pragma unroll
    for (int i = 0; i < 6; ++i)
        kr[i] = (i < nk) ? __builtin_nontemporal_load(&bucket[slot + 8 * i]) : 0u;

    const uint4*  e16 = (const uint4*)ent16;    // row = 8 x uint4 (8 bf16 ch each)
    const float4* w4  = (const float4*)weight;

    float4 acc0 = make_float4(0.f, 0.f, 0.f, 0.f);
    float4 acc1 = make_float4(0.f, 0.f, 0.f, 0.f);

    #pragma unroll
    for (int i = 0; i < 6; ++i) {
        if (i < nk) {
            unsigned key  = kr[i];
            unsigned tail = key & 0xFFFFFu;
            unsigned rel  = key >> 20;
            uint4 ev = e16[(size_t)tail * 8 + q];
            const float4* wp = w4 + rel * 16 + q * 2;
            float4 w0 = wp[0], w1 = wp[1];
            float e0 = __uint_as_float(ev.x << 16);
            float e1 = __uint_as_float(ev.x & 0xFFFF0000u);
            float e2 = __uint_as_float(ev.y << 16);
            float e3 = __uint_as_float(ev.y & 0xFFFF0000u);
            float e4 = __uint_as_float(ev.z << 16);
            float e5 = __uint_as_float(ev.z & 0xFFFF0000u);
            float e6 = __uint_as_float(ev.w << 16);
            float e7 = __uint_as_float(ev.w & 0xFFFF0000u);
            acc0.x += e0 * w0.x; acc0.y += e1 * w0.y;
            acc0.z += e2 * w0.z; acc0.w += e3 * w0.w;
            acc1.x += e4 * w1.x; acc1.y += e5 * w1.y;
            acc1.z += e6 * w1.z; acc1.w += e7 * w1.w;
        }
    }

    // cross-slot reduce: fold slot bits (8, 16, 32)
    #pragma unroll
    for (int off = 8; off <= 32; off <<= 1) {
        acc0.x += __shfl_xor(acc0.x, off); acc0.y += __shfl_xor(acc0.y, off);
        acc0.z += __shfl_xor(acc0.z, off); acc0.w += __shfl_xor(acc0.w, off);
        acc1.x += __shfl_xor(acc1.x, off); acc1.y += __shfl_xor(acc1.y, off);
        acc1.z += __shfl_xor(acc1.z, off); acc1.w += __shfl_xor(acc1.w, off);
    }

    if (slot == 0) {
        float inv = 1.0f / fmaxf((float)c, 1.0f);
        acc0.x *= inv; acc0.y *= inv; acc0.z *= inv; acc0.w *= inv;
        acc1.x *= inv; acc1.y *= inv; acc1.z *= inv; acc1.w *= inv;
        float4* o = (float4*)out_ent + (size_t)ent * 16 + q * 2;
        o[0] = acc0;
        o[1] = acc1;
    }
}

// ============================================================================
// Dispatch 3 (tier-3, R6-proven): fp32 segmented reduce, 2 entities/wave.
// ============================================================================
__global__ __launch_bounds__(256, 4) void reduce_kernel(
    const float* __restrict__ entity_emb,
    const float* __restrict__ weight,
    const unsigned* __restrict__ cursor,
    const unsigned* __restrict__ keys,
    float* __restrict__ out_ent)
{
    const int gtid = blockIdx.x * 256 + threadIdx.x;
    const int wave = gtid >> 6;
    const int lane = threadIdx.x & 63;
    const int half = lane >> 5;
    const int l32  = lane & 31;
    const int slot = l32 >> 3;
    const int q    = lane & 7;

    const int ent = wave * 2 + half;

    unsigned c = cursor[ent];
    if (c > CAP) c = CAP;
    const unsigned* bucket = keys + (unsigned)ent * CAP;

    const int nk = ((int)c > slot) ? (int)((c - (unsigned)slot + 3u) >> 2) : 0;

    unsigned kr[12];
    #pragma unroll
    for (int i = 0; i < 12; ++i)
        kr[i] = (i < nk) ? __builtin_nontemporal_load(&bucket[slot + 4 * i]) : 0u;

    const float4* emb4 = (const float4*)entity_emb;
    const float4* w4   = (const float4*)weight;

    float4 acc0 = make_float4(0.f, 0.f, 0.f, 0.f);
    float4 acc1 = make_float4(0.f, 0.f, 0.f, 0.f);

    #pragma unroll
    for (int i = 0; i < 12; ++i) {
        if (i < nk) {
            unsigned key  = kr[i];
            unsigned tail = key & 0xFFFFFu;
            unsigned rel  = key >> 20;
            const float4* ep = emb4 + (size_t)tail * 16 + q * 2;
            const float4* wp = w4 + rel * 16 + q * 2;
            float4 e0 = ep[0], e1 = ep[1];
            float4 w0 = wp[0], w1 = wp[1];
            acc0.x += e0.x * w0.x; acc0.y += e0.y * w0.y;
            acc0.z += e0.z * w0.z; acc0.w += e0.w * w0.w;
            acc1.x += e1.x * w1.x; acc1.y += e1.y * w1.y;
            acc1.z += e1.z * w1.z; acc1.w += e1.w * w1.w;
        }
    }

    #pragma unroll
    for (int off = 8; off <= 16; off <<= 1) {
        acc0.x += __shfl_xor(acc0.x, off); acc0.y += __shfl_xor(acc0.y, off);
        acc0.z += __shfl_xor(acc0.z, off); acc0.w += __shfl_xor(acc0.w, off);
        acc1.x += __shfl_xor(acc1.x, off); acc1.y += __shfl_xor(acc1.y, off);
        acc1.z += __shfl_xor(acc1.z, off); acc1.w += __shfl_xor(acc1.w, off);
    }

    if (slot == 0) {
        float inv = 1.0f / fmaxf((float)c, 1.0f);
        acc0.x *= inv; acc0.y *= inv; acc0.z *= inv; acc0.w *= inv;
        acc1.x *= inv; acc1.y *= inv; acc1.z *= inv; acc1.w *= inv;
        float4* o = (float4*)out_ent + (size_t)ent * 16 + q * 2;
        o[0] = acc0;
        o[1] = acc1;
    }
}

// ============================================================================
// Fallback (ws too small): R1-proven atomic path.
// ============================================================================
__global__ __launch_bounds__(256) void scatter_kernel(
    const float* __restrict__ entity_emb,
    const int* __restrict__ edge_index, const int* __restrict__ edge_type,
    const float* __restrict__ weight,
    float* __restrict__ ent_sum, float* __restrict__ cnt)
{
    int idx = blockIdx.x * 256 + threadIdx.x;
    int e = idx >> 4;
    int q = idx & 15;
    if (e >= N_EDGES) return;
    int head = edge_index[e];
    int tail = edge_index[N_EDGES + e];
    int rel  = edge_type[e] - 2;
    const float4* emb4 = (const float4*)entity_emb;
    const float4* w4   = (const float4*)weight;
    float4 ev = emb4[(size_t)tail * 16 + q];
    float4 wv = w4[rel * 16 + q];
    float* dst = ent_sum + (size_t)head * 64 + q * 4;
    atomicAdd(dst + 0, ev.x * wv.x);
    atomicAdd(dst + 1, ev.y * wv.y);
    atomicAdd(dst + 2, ev.z * wv.z);
    atomicAdd(dst + 3, ev.w * wv.w);
    if (q == 0) atomicAdd(&cnt[head], 1.0f);
}

__global__ __launch_bounds__(256) void divide_kernel(
    float* __restrict__ ent, const float* __restrict__ cnt)
{
    int idx = blockIdx.x * 256 + threadIdx.x;
    if (idx >= N_ENT * 16) return;
    int row = idx >> 4;
    float inv = 1.0f / fmaxf(cnt[row], 1.0f);
    float4* p = (float4*)ent;
    float4 v = p[idx];
    v.x *= inv; v.y *= inv; v.z *= inv; v.w *= inv;
    p[idx] = v;
}

__global__ __launch_bounds__(256) void gemm_fallback_kernel(
    const float* __restrict__ ia, const float* __restrict__ ua,
    const float* __restrict__ A,
    float* __restrict__ out_item, float* __restrict__ out_user)
{
    int tile = blockIdx.x;
    const float* M; float* out; int N, tt;
    if (tile < ITEM_TILES) { M = ia; out = out_item; N = N_ITM; tt = tile; }
    else                   { M = ua; out = out_user; N = N_USR; tt = tile - ITEM_TILES; }
    const int row0 = tt * 64;
    const int t  = threadIdx.x;
    const int ci = t & 15;
    const int r0 = (t >> 4) * 4;
    const float4* A4 = (const float4*)A;
    const float4* M4 = (const float4*)M;
    int r[4];
    #pragma unroll
    for (int j = 0; j < 4; ++j) {
        int rr = row0 + r0 + j;
        r[j] = (rr < N) ? rr : (N - 1);
    }
    float4 acc[4];
    #pragma unroll
    for (int j = 0; j < 4; ++j) acc[j] = make_float4(0.f, 0.f, 0.f, 0.f);
    #pragma unroll 4
    for (int k4 = 0; k4 < 16; ++k4) {
        float4 a0 = A4[(k4 * 4 + 0) * 16 + ci];
        float4 a1 = A4[(k4 * 4 + 1) * 16 + ci];
        float4 a2 = A4[(k4 * 4 + 2) * 16 + ci];
        float4 a3 = A4[(k4 * 4 + 3) * 16 + ci];
        #pragma unroll
        for (int j = 0; j < 4; ++j) {
            float4 mv = M4[(size_t)r[j] * 16 + k4];
            acc[j].x += mv.x * a0.x + mv.y * a1.x + mv.z * a2.x + mv.w * a3.x;
            acc[j].y += mv.x * a0.y + mv.y * a1.y + mv.z * a2.y + mv.w * a3.y;
            acc[j].z += mv.x * a0.z + mv.y * a1.z + mv.z * a2.z + mv.w * a3.z;
            acc[j].w += mv.x * a0.w + mv.y * a1.w + mv.z * a2.w + mv.w * a3.w;
        }
    }
    float4* out4 = (float4*)out;
    #pragma unroll
    for (int j = 0; j < 4; ++j) {
        int rr = row0 + r0 + j;
        if (rr < N) {
            float4 v = acc[j];
            v.x *= 2.f; v.y *= 2.f; v.z *= 2.f; v.w *= 2.f;
            out4[(size_t)rr * 16 + ci] = v;
        }
    }
}

// ============================================================================
extern "C" void kernel_launch(void* const* d_in, const int* in_sizes, int n_in,
                              void* d_out, int out_size, void* d_ws, size_t ws_size,
                              hipStream_t stream) {
    const float* entity_emb = (const float*)d_in[0];
    const float* aspect_emb = (const float*)d_in[3];
    const int*   edge_index = (const int*)d_in[4];
    const int*   edge_type  = (const int*)d_in[5];
    const float* ua_mat     = (const float*)d_in[6];
    const float* ia_mat     = (const float*)d_in[7];
    const float* weight     = (const float*)d_in[8];

    float* out_item = (float*)d_out;
    float* out_ent  = out_item + (size_t)N_ITM * CH;
    float* out_user = out_ent  + (size_t)N_ENT * CH;

    size_t need_fc  = ((size_t)N_ENT + (size_t)N_ENT * CAP) * 4;          // ~19.6 MB
    size_t need_bf  = need_fc + (size_t)N_ENT * CH * 2;                   // ~32.4 MB

    if (ws_size >= need_bf) {
        const int cstride = 1;      // R9: padding null/unverifiable; keep dense
        unsigned* cursor = (unsigned*)d_ws;
        unsigned* keys   = cursor + (size_t)N_ENT * cstride;
        unsigned short* ent16 = (unsigned short*)(keys + (size_t)N_ENT * CAP);

        (void)hipMemsetAsync(cursor, 0, (size_t)N_ENT * cstride * 4, stream);
        scatter_gemm_kernel<<<SCAT_BLKS, 256, 0, stream>>>(
            edge_index, edge_type, entity_emb, aspect_emb, ia_mat, ua_mat,
            cursor, keys, ent16, cstride, out_item, out_user);
        // 1 entity/wave: N_ENT waves = 25000 blocks
        reduce_bf16_kernel<<<(N_ENT * 64) / 256, 256, 0, stream>>>(
            ent16, weight, cursor, keys, cstride, out_ent);
    } else if (ws_size >= need_fc) {
        unsigned* cursor = (unsigned*)d_ws;
        unsigned* keys   = cursor + N_ENT;

        (void)hipMemsetAsync(cursor, 0, (size_t)N_ENT * 4, stream);
        scatter_gemm_kernel<<<SCAT_BLKS, 256, 0, stream>>>(
            edge_index, edge_type, entity_emb, aspect_emb, ia_mat, ua_mat,
            cursor, keys, nullptr, 1, out_item, out_user);
        reduce_kernel<<<(N_ENT / 2) * 64 / 256, 256, 0, stream>>>(
            entity_emb, weight, cursor, keys, out_ent);
    } else {
        float* cnt = (float*)d_ws;
        (void)hipMemsetAsync(out_ent, 0, (size_t)N_ENT * CH * sizeof(float), stream);
        (void)hipMemsetAsync(cnt, 0, (size_t)N_ENT * sizeof(float), stream);
        scatter_kernel<<<(N_EDGES * 16 + 255) / 256, 256, 0, stream>>>(
            entity_emb, edge_index, edge_type, weight, out_ent, cnt);
        divide_kernel<<<(N_ENT * 16 + 255) / 256, 256, 0, stream>>>(out_ent, cnt);
        gemm_fallback_kernel<<<TOT_TILES, 256, 0, stream>>>(
            ia_mat, ua_mat, aspect_emb, out_item, out_user);
    }
}

// Round 11
// 273.911 us; speedup vs baseline: 1.0749x; 1.0277x over previous
//
#include <hip/hip_runtime.h>

#define N_EDGES   1250000
#define N_ENT     100000
#define N_USR     100000
#define N_ITM     50000
#define CH        64
#define CAP       48        // bucket capacity; deg ~ Poisson(12.5), P(>48) ~ 1e-14

#define ITEM_TILES ((N_ITM + 63) / 64)   // 782
#define USER_TILES ((N_USR + 63) / 64)   // 1563
#define TOT_TILES  (ITEM_TILES + USER_TILES)   // 2345

#define EPT 2                                     // R2-proven: 2 edges/thread
#define SCAT_BLKS ((N_EDGES + 256*EPT - 1) / (256*EPT))   // 2442 >= TOT_TILES

// ---- two-pass sort parameters (R11) ----------------------------------------
#define NR    256                         // head ranges
#define RDIV  391                         // entities per range (256*391 >= 100000)
#define RCAP  5376                        // region capacity: mean 4883 + 7 sigma
#define P1_BLOCKS ((N_EDGES + 2047) / 2048)   // 611 blocks x 512 thr x 4 edges

// round-to-nearest-even fp32 -> bf16
__device__ __forceinline__ unsigned short bf16_rne(float f) {
    unsigned u = __float_as_uint(f);
    unsigned r = u + 0x7FFFu + ((u >> 16) & 1u);
    return (unsigned short)(r >> 16);
}

// ============================================================================
// R11 pass 1: LDS-histogram range bucketing. Replaces 1.25M global cursor
// atomics (~90ns service each, the R3-R10-proven scatter floor) with 1.25M
// LDS atomics (cycle-scale) + ~156K global range-base atomics (8x fewer).
// Each block: histogram 2048 edges over 256 head-ranges -> claim global
// bases -> scatter packed (head|tail|rel) u64 records into per-range regions
// (block-contiguous chunks). bf16 conversion rides in the tail.
// ============================================================================
__global__ __launch_bounds__(512, 4) void sort_pass1_kernel(
    const int* __restrict__ edge_index,
    const int* __restrict__ edge_type,
    const float* __restrict__ entity_emb,
    unsigned* __restrict__ range_cnt,
    unsigned long long* __restrict__ range_buf,
    unsigned short* __restrict__ ent16)
{
    __shared__ unsigned hist[NR];
    const int tid = threadIdx.x;
    if (tid < NR) hist[tid] = 0;
    __syncthreads();

    const int base_e = blockIdx.x * 2048 + tid;
    int head[4], tail[4], rel[4], rng[4];
    bool v[4];
    #pragma unroll
    for (int i = 0; i < 4; ++i) {
        int e = base_e + i * 512;
        v[i] = (e < N_EDGES);
        int le = v[i] ? e : 0;
        head[i] = __builtin_nontemporal_load(&edge_index[le]);
        tail[i] = __builtin_nontemporal_load(&edge_index[N_EDGES + le]);
        rel[i]  = __builtin_nontemporal_load(&edge_type[le]) - 2;
        rng[i]  = head[i] / RDIV;          // compiler magic-muls the /391
        if (v[i]) atomicAdd(&hist[rng[i]], 1u);
    }
    __syncthreads();

    // claim global base per nonzero range (~256 global atomics per block)
    if (tid < NR) {
        unsigned cnt = hist[tid];
        unsigned b = 0;
        if (cnt) b = atomicAdd(&range_cnt[tid], cnt);
        hist[tid] = b;                     // hist now counts up from base
    }
    __syncthreads();

    #pragma unroll
    for (int i = 0; i < 4; ++i) {
        if (v[i]) {
            unsigned off = atomicAdd(&hist[rng[i]], 1u);
            if (off < RCAP)
                range_buf[(size_t)rng[i] * RCAP + off] =
                    (unsigned long long)(unsigned)head[i]
                    | ((unsigned long long)(unsigned)tail[i] << 17)
                    | ((unsigned long long)(unsigned)rel[i]  << 34);
        }
    }

    // ---- bf16 conversion tail (grid-stride streaming) ----------------------
    const int gtid = blockIdx.x * 512 + tid;
    const int nth  = P1_BLOCKS * 512;
    const float4* src = (const float4*)entity_emb;
    ushort4* dst = (ushort4*)ent16;
    for (int g = gtid; g < N_ENT * 16; g += nth) {
        float4 vv = src[g];
        ushort4 o;
        o.x = bf16_rne(vv.x); o.y = bf16_rne(vv.y);
        o.z = bf16_rne(vv.z); o.w = bf16_rne(vv.w);
        dst[g] = o;
    }
}

// ============================================================================
// R11 pass 2: per-range bucket build. One block per range; in-bucket
// positions via LDS counters over the range's 391 entities; emits cursor +
// keys in EXACTLY the format the proven reduce consumes. keys writes land
// in a 75KB window -> L2-local.
// ============================================================================
__global__ __launch_bounds__(512, 4) void sort_pass2_kernel(
    const unsigned* __restrict__ range_cnt,
    const unsigned long long* __restrict__ range_buf,
    unsigned* __restrict__ cursor,
    unsigned* __restrict__ keys)
{
    __shared__ unsigned lcnt[RDIV];
    const int r   = blockIdx.x;
    const int tid = threadIdx.x;
    if (tid < RDIV) lcnt[tid] = 0;
    __syncthreads();

    unsigned n = range_cnt[r];
    if (n > RCAP) n = RCAP;
    const unsigned long long* buf = range_buf + (size_t)r * RCAP;
    for (unsigned i = tid; i < n; i += 512) {
        unsigned long long rec = buf[i];
        unsigned head = (unsigned)(rec & 0x1FFFFu);
        unsigned tail = (unsigned)((rec >> 17) & 0x1FFFFu);
        unsigned rel  = (unsigned)((rec >> 34) & 0xFu);
        unsigned local = head - (unsigned)r * RDIV;   // in [0, RDIV)
        unsigned pos = atomicAdd(&lcnt[local], 1u);
        if (pos < CAP)
            keys[head * CAP + pos] = tail | (rel << 20);
    }
    __syncthreads();
    if (tid < RDIV) {
        int ent = r * RDIV + tid;
        if (ent < N_ENT) cursor[ent] = lcnt[tid];
    }
}

// ============================================================================
// R10-proven fused kernel (fallback tier when ws < sort-tier size):
// scatter (atomics issued early, waited late) + bf16 conversion + GEMM tail.
// ============================================================================
__global__ __launch_bounds__(256, 4) void scatter_gemm_kernel(
    const int*   __restrict__ edge_index,
    const int*   __restrict__ edge_type,
    const float* __restrict__ entity_emb,
    const float* __restrict__ aspect_emb,
    const float* __restrict__ ia_mat,
    const float* __restrict__ ua_mat,
    unsigned* __restrict__ cursor,
    unsigned* __restrict__ keys,
    unsigned short* __restrict__ ent16,     // nullptr => skip conversion
    float* __restrict__ out_item,
    float* __restrict__ out_user)
{
    const int tid = blockIdx.x * 256 + threadIdx.x;
    const int nth = SCAT_BLKS * 256;

    bool  cvalid[3];
    float4 cv[3];
    {
        const float4* src = (const float4*)entity_emb;
        #pragma unroll
        for (int k = 0; k < 3; ++k) {
            int g = tid + k * nth;
            cvalid[k] = (ent16 != nullptr) && (g < N_ENT * 16);
            cv[k] = cvalid[k] ? src[g] : make_float4(0.f, 0.f, 0.f, 0.f);
        }
    }

    const int eA = blockIdx.x * (256 * EPT) + threadIdx.x;
    const int eB = eA + 256;
    const bool vA = (eA < N_EDGES);
    const bool vB = (eB < N_EDGES);
    {
        const int la = vA ? eA : 0;
        const int lb = vB ? eB : 0;

        int headA_ = __builtin_nontemporal_load(&edge_index[la]);
        int headB_ = __builtin_nontemporal_load(&edge_index[lb]);
        int tailA  = __builtin_nontemporal_load(&edge_index[N_EDGES + la]);
        int tailB  = __builtin_nontemporal_load(&edge_index[N_EDGES + lb]);
        int relA   = __builtin_nontemporal_load(&edge_type[la]) - 2;
        int relB   = __builtin_nontemporal_load(&edge_type[lb]) - 2;

        unsigned keyA = (unsigned)tailA | ((unsigned)relA << 20);
        unsigned keyB = (unsigned)tailB | ((unsigned)relB << 20);
        unsigned posA = 0xFFFFFFFFu, posB = 0xFFFFFFFFu;
        if (vA) posA = atomicAdd(&cursor[headA_], 1u);
        if (vB) posB = atomicAdd(&cursor[headB_], 1u);

        if (ent16) {
            ushort4* dst = (ushort4*)ent16;
            #pragma unroll
            for (int k = 0; k < 3; ++k) {
                if (cvalid[k]) {
                    int g = tid + k * nth;
                    ushort4 o;
                    o.x = bf16_rne(cv[k].x); o.y = bf16_rne(cv[k].y);
                    o.z = bf16_rne(cv[k].z); o.w = bf16_rne(cv[k].w);
                    dst[g] = o;
                }
            }
        }

        int tile = blockIdx.x;
        if (tile < TOT_TILES) {
            const float* M; float* out; int N, tt;
            if (tile < ITEM_TILES) { M = ia_mat; out = out_item; N = N_ITM; tt = tile; }
            else                   { M = ua_mat; out = out_user; N = N_USR; tt = tile - ITEM_TILES; }
            const int row0 = tt * 64;
            const int t  = threadIdx.x;
            const int ci = t & 15;
            const int r0 = (t >> 4) * 4;
            const float4* A4 = (const float4*)aspect_emb;
            const float4* M4 = (const float4*)M;
            int r[4];
            #pragma unroll
            for (int j = 0; j < 4; ++j) {
                int rr = row0 + r0 + j;
                r[j] = (rr < N) ? rr : (N - 1);
            }
            float4 acc[4];
            #pragma unroll
            for (int j = 0; j < 4; ++j) acc[j] = make_float4(0.f, 0.f, 0.f, 0.f);
            #pragma unroll 4
            for (int k4 = 0; k4 < 16; ++k4) {
                float4 a0 = A4[(k4 * 4 + 0) * 16 + ci];
                float4 a1 = A4[(k4 * 4 + 1) * 16 + ci];
                float4 a2 = A4[(k4 * 4 + 2) * 16 + ci];
                float4 a3 = A4[(k4 * 4 + 3) * 16 + ci];
                #pragma unroll
                for (int j = 0; j < 4; ++j) {
                    float4 mv = M4[(size_t)r[j] * 16 + k4];
                    acc[j].x += mv.x * a0.x + mv.y * a1.x + mv.z * a2.x + mv.w * a3.x;
                    acc[j].y += mv.x * a0.y + mv.y * a1.y + mv.z * a2.y + mv.w * a3.y;
                    acc[j].z += mv.x * a0.z + mv.y * a1.z + mv.z * a2.z + mv.w * a3.z;
                    acc[j].w += mv.x * a0.w + mv.y * a1.w + mv.z * a2.w + mv.w * a3.w;
                }
            }
            float4* out4 = (float4*)out;
            #pragma unroll
            for (int j = 0; j < 4; ++j) {
                int rr = row0 + r0 + j;
                if (rr < N) {
                    float4 v = acc[j];
                    v.x *= 2.f; v.y *= 2.f; v.z *= 2.f; v.w *= 2.f;
                    out4[(size_t)rr * 16 + ci] = v;
                }
            }
        }

        if (vA && posA < CAP)
            keys[(unsigned)headA_ * CAP + posA] = keyA;
        if (vB && posB < CAP)
            keys[(unsigned)headB_ * CAP + posB] = keyB;
    }
}

// ============================================================================
// Proven reduce: bf16 rows, ONE entity per wave, 8 slots x 8 q-lanes,
// keys prefetched. Unchanged (consumed by both sort tier and R10 tier).
// ============================================================================
__global__ __launch_bounds__(256, 8) void reduce_bf16_kernel(
    const unsigned short* __restrict__ ent16,
    const float* __restrict__ weight,
    const unsigned* __restrict__ cursor,
    const unsigned* __restrict__ keys,
    float* __restrict__ out_ent)
{
    const int gtid = blockIdx.x * 256 + threadIdx.x;
    const int ent  = gtid >> 6;
    const int lane = threadIdx.x & 63;
    const int slot = lane >> 3;
    const int q    = lane & 7;

    unsigned c = cursor[ent];
    if (c > CAP) c = CAP;
    const unsigned* bucket = keys + (unsigned)ent * CAP;

    const int nk = ((int)c > slot) ? (int)((c - (unsigned)slot + 7u) >> 3) : 0;

    unsigned kr[6];
    #pragma unroll
    for (int i = 0; i < 6; ++i)
        kr[i] = (i < nk) ? __builtin_nontemporal_load(&bucket[slot + 8 * i]) : 0u;

    const uint4*  e16 = (const uint4*)ent16;
    const float4* w4  = (const float4*)weight;

    float4 acc0 = make_float4(0.f, 0.f, 0.f, 0.f);
    float4 acc1 = make_float4(0.f, 0.f, 0.f, 0.f);

    #pragma unroll
    for (int i = 0; i < 6; ++i) {
        if (i < nk) {
            unsigned key  = kr[i];
            unsigned tail = key & 0xFFFFFu;
            unsigned rel  = key >> 20;
            uint4 ev = e16[(size_t)tail * 8 + q];
            const float4* wp = w4 + rel * 16 + q * 2;
            float4 w0 = wp[0], w1 = wp[1];
            float e0 = __uint_as_float(ev.x << 16);
            float e1 = __uint_as_float(ev.x & 0xFFFF0000u);
            float e2 = __uint_as_float(ev.y << 16);
            float e3 = __uint_as_float(ev.y & 0xFFFF0000u);
            float e4 = __uint_as_float(ev.z << 16);
            float e5 = __uint_as_float(ev.z & 0xFFFF0000u);
            float e6 = __uint_as_float(ev.w << 16);
            float e7 = __uint_as_float(ev.w & 0xFFFF0000u);
            acc0.x += e0 * w0.x; acc0.y += e1 * w0.y;
            acc0.z += e2 * w0.z; acc0.w += e3 * w0.w;
            acc1.x += e4 * w1.x; acc1.y += e5 * w1.y;
            acc1.z += e6 * w1.z; acc1.w += e7 * w1.w;
        }
    }

    #pragma unroll
    for (int off = 8; off <= 32; off <<= 1) {
        acc0.x += __shfl_xor(acc0.x, off); acc0.y += __shfl_xor(acc0.y, off);
        acc0.z += __shfl_xor(acc0.z, off); acc0.w += __shfl_xor(acc0.w, off);
        acc1.x += __shfl_xor(acc1.x, off); acc1.y += __shfl_xor(acc1.y, off);
        acc1.z += __shfl_xor(acc1.z, off); acc1.w += __shfl_xor(acc1.w, off);
    }

    if (slot == 0) {
        float inv = 1.0f / fmaxf((float)c, 1.0f);
        acc0.x *= inv; acc0.y *= inv; acc0.z *= inv; acc0.w *= inv;
        acc1.x *= inv; acc1.y *= inv; acc1.z *= inv; acc1.w *= inv;
        float4* o = (float4*)out_ent + (size_t)ent * 16 + q * 2;
        o[0] = acc0;
        o[1] = acc1;
    }
}

// ============================================================================
// Tier-3 (R6-proven): fp32 segmented reduce, 2 entities/wave.
// ============================================================================
__global__ __launch_bounds__(256, 4) void reduce_kernel(
    const float* __restrict__ entity_emb,
    const float* __restrict__ weight,
    const unsigned* __restrict__ cursor,
    const unsigned* __restrict__ keys,
    float* __restrict__ out_ent)
{
    const int gtid = blockIdx.x * 256 + threadIdx.x;
    const int wave = gtid >> 6;
    const int lane = threadIdx.x & 63;
    const int half = lane >> 5;
    const int l32  = lane & 31;
    const int slot = l32 >> 3;
    const int q    = lane & 7;

    const int ent = wave * 2 + half;

    unsigned c = cursor[ent];
    if (c > CAP) c = CAP;
    const unsigned* bucket = keys + (unsigned)ent * CAP;

    const int nk = ((int)c > slot) ? (int)((c - (unsigned)slot + 3u) >> 2) : 0;

    unsigned kr[12];
    #pragma unroll
    for (int i = 0; i < 12; ++i)
        kr[i] = (i < nk) ? __builtin_nontemporal_load(&bucket[slot + 4 * i]) : 0u;

    const float4* emb4 = (const float4*)entity_emb;
    const float4* w4   = (const float4*)weight;

    float4 acc0 = make_float4(0.f, 0.f, 0.f, 0.f);
    float4 acc1 = make_float4(0.f, 0.f, 0.f, 0.f);

    #pragma unroll
    for (int i = 0; i < 12; ++i) {
        if (i < nk) {
            unsigned key  = kr[i];
            unsigned tail = key & 0xFFFFFu;
            unsigned rel  = key >> 20;
            const float4* ep = emb4 + (size_t)tail * 16 + q * 2;
            const float4* wp = w4 + rel * 16 + q * 2;
            float4 e0 = ep[0], e1 = ep[1];
            float4 w0 = wp[0], w1 = wp[1];
            acc0.x += e0.x * w0.x; acc0.y += e0.y * w0.y;
            acc0.z += e0.z * w0.z; acc0.w += e0.w * w0.w;
            acc1.x += e1.x * w1.x; acc1.y += e1.y * w1.y;
            acc1.z += e1.z * w1.z; acc1.w += e1.w * w1.w;
        }
    }

    #pragma unroll
    for (int off = 8; off <= 16; off <<= 1) {
        acc0.x += __shfl_xor(acc0.x, off); acc0.y += __shfl_xor(acc0.y, off);
        acc0.z += __shfl_xor(acc0.z, off); acc0.w += __shfl_xor(acc0.w, off);
        acc1.x += __shfl_xor(acc1.x, off); acc1.y += __shfl_xor(acc1.y, off);
        acc1.z += __shfl_xor(acc1.z, off); acc1.w += __shfl_xor(acc1.w, off);
    }

    if (slot == 0) {
        float inv = 1.0f / fmaxf((float)c, 1.0f);
        acc0.x *= inv; acc0.y *= inv; acc0.z *= inv; acc0.w *= inv;
        acc1.x *= inv; acc1.y *= inv; acc1.z *= inv; acc1.w *= inv;
        float4* o = (float4*)out_ent + (size_t)ent * 16 + q * 2;
        o[0] = acc0;
        o[1] = acc1;
    }
}

// ============================================================================
// Standalone GEMM (proven): one 64x64 tile per block.
// ============================================================================
__global__ __launch_bounds__(256) void gemm_fallback_kernel(
    const float* __restrict__ ia, const float* __restrict__ ua,
    const float* __restrict__ A,
    float* __restrict__ out_item, float* __restrict__ out_user)
{
    int tile = blockIdx.x;
    const float* M; float* out; int N, tt;
    if (tile < ITEM_TILES) { M = ia; out = out_item; N = N_ITM; tt = tile; }
    else                   { M = ua; out = out_user; N = N_USR; tt = tile - ITEM_TILES; }
    const int row0 = tt * 64;
    const int t  = threadIdx.x;
    const int ci = t & 15;
    const int r0 = (t >> 4) * 4;
    const float4* A4 = (const float4*)A;
    const float4* M4 = (const float4*)M;
    int r[4];
    #pragma unroll
    for (int j = 0; j < 4; ++j) {
        int rr = row0 + r0 + j;
        r[j] = (rr < N) ? rr : (N - 1);
    }
    float4 acc[4];
    #pragma unroll
    for (int j = 0; j < 4; ++j) acc[j] = make_float4(0.f, 0.f, 0.f, 0.f);
    #pragma unroll 4
    for (int k4 = 0; k4 < 16; ++k4) {
        float4 a0 = A4[(k4 * 4 + 0) * 16 + ci];
        float4 a1 = A4[(k4 * 4 + 1) * 16 + ci];
        float4 a2 = A4[(k4 * 4 + 2) * 16 + ci];
        float4 a3 = A4[(k4 * 4 + 3) * 16 + ci];
        #pragma unroll
        for (int j = 0; j < 4; ++j) {
            float4 mv = M4[(size_t)r[j] * 16 + k4];
            acc[j].x += mv.x * a0.x + mv.y * a1.x + mv.z * a2.x + mv.w * a3.x;
            acc[j].y += mv.x * a0.y + mv.y * a1.y + mv.z * a2.y + mv.w * a3.y;
            acc[j].z += mv.x * a0.z + mv.y * a1.z + mv.z * a2.z + mv.w * a3.z;
            acc[j].w += mv.x * a0.w + mv.y * a1.w + mv.z * a2.w + mv.w * a3.w;
        }
    }
    float4* out4 = (float4*)out;
    #pragma unroll
    for (int j = 0; j < 4; ++j) {
        int rr = row0 + r0 + j;
        if (rr < N) {
            float4 v = acc[j];
            v.x *= 2.f; v.y *= 2.f; v.z *= 2.f; v.w *= 2.f;
            out4[(size_t)rr * 16 + ci] = v;
        }
    }
}

// ============================================================================
// Fallback (ws tiny): R1-proven atomic path.
// ============================================================================
__global__ __launch_bounds__(256) void scatter_kernel(
    const float* __restrict__ entity_emb,
    const int* __restrict__ edge_index, const int* __restrict__ edge_type,
    const float* __restrict__ weight,
    float* __restrict__ ent_sum, float* __restrict__ cnt)
{
    int idx = blockIdx.x * 256 + threadIdx.x;
    int e = idx >> 4;
    int q = idx & 15;
    if (e >= N_EDGES) return;
    int head = edge_index[e];
    int tail = edge_index[N_EDGES + e];
    int rel  = edge_type[e] - 2;
    const float4* emb4 = (const float4*)entity_emb;
    const float4* w4   = (const float4*)weight;
    float4 ev = emb4[(size_t)tail * 16 + q];
    float4 wv = w4[rel * 16 + q];
    float* dst = ent_sum + (size_t)head * 64 + q * 4;
    atomicAdd(dst + 0, ev.x * wv.x);
    atomicAdd(dst + 1, ev.y * wv.y);
    atomicAdd(dst + 2, ev.z * wv.z);
    atomicAdd(dst + 3, ev.w * wv.w);
    if (q == 0) atomicAdd(&cnt[head], 1.0f);
}

__global__ __launch_bounds__(256) void divide_kernel(
    float* __restrict__ ent, const float* __restrict__ cnt)
{
    int idx = blockIdx.x * 256 + threadIdx.x;
    if (idx >= N_ENT * 16) return;
    int row = idx >> 4;
    float inv = 1.0f / fmaxf(cnt[row], 1.0f);
    float4* p = (float4*)ent;
    float4 v = p[idx];
    v.x *= inv; v.y *= inv; v.z *= inv; v.w *= inv;
    p[idx] = v;
}

// ============================================================================
extern "C" void kernel_launch(void* const* d_in, const int* in_sizes, int n_in,
                              void* d_out, int out_size, void* d_ws, size_t ws_size,
                              hipStream_t stream) {
    const float* entity_emb = (const float*)d_in[0];
    const float* aspect_emb = (const float*)d_in[3];
    const int*   edge_index = (const int*)d_in[4];
    const int*   edge_type  = (const int*)d_in[5];
    const float* ua_mat     = (const float*)d_in[6];
    const float* ia_mat     = (const float*)d_in[7];
    const float* weight     = (const float*)d_in[8];

    float* out_item = (float*)d_out;
    float* out_ent  = out_item + (size_t)N_ITM * CH;
    float* out_user = out_ent  + (size_t)N_ENT * CH;

    size_t need_fc   = ((size_t)N_ENT + (size_t)N_ENT * CAP) * 4;         // ~19.6 MB
    size_t need_bf   = need_fc + (size_t)N_ENT * CH * 2;                  // ~32.4 MB
    size_t need_sort = (size_t)NR * RCAP * 8                              // range_buf 11.0 MB
                     + (size_t)N_ENT * 4                                  // cursor
                     + (size_t)N_ENT * CAP * 4                            // keys
                     + (size_t)N_ENT * CH * 2                             // ent16
                     + (size_t)NR * 4;                                    // range_cnt  => ~43.4 MB

    if (ws_size >= need_sort) {
        // ---- R11 tier: two-pass LDS sort, no per-edge global atomics -------
        unsigned long long* range_buf = (unsigned long long*)d_ws;        // 8-aligned
        unsigned* cursor = (unsigned*)(range_buf + (size_t)NR * RCAP);
        unsigned* keys   = cursor + N_ENT;
        unsigned short* ent16 = (unsigned short*)(keys + (size_t)N_ENT * CAP);
        unsigned* range_cnt = (unsigned*)(ent16 + (size_t)N_ENT * CH);

        (void)hipMemsetAsync(range_cnt, 0, (size_t)NR * 4, stream);
        sort_pass1_kernel<<<P1_BLOCKS, 512, 0, stream>>>(
            edge_index, edge_type, entity_emb, range_cnt, range_buf, ent16);
        sort_pass2_kernel<<<NR, 512, 0, stream>>>(
            range_cnt, range_buf, cursor, keys);
        gemm_fallback_kernel<<<TOT_TILES, 256, 0, stream>>>(
            ia_mat, ua_mat, aspect_emb, out_item, out_user);
        reduce_bf16_kernel<<<(N_ENT * 64) / 256, 256, 0, stream>>>(
            ent16, weight, cursor, keys, out_ent);
    } else if (ws_size >= need_bf) {
        // ---- R10 tier (proven best atomic path) ----------------------------
        unsigned* cursor = (unsigned*)d_ws;
        unsigned* keys   = cursor + N_ENT;
        unsigned short* ent16 = (unsigned short*)(keys + (size_t)N_ENT * CAP);

        (void)hipMemsetAsync(cursor, 0, (size_t)N_ENT * 4, stream);
        scatter_gemm_kernel<<<SCAT_BLKS, 256, 0, stream>>>(
            edge_index, edge_type, entity_emb, aspect_emb, ia_mat, ua_mat,
            cursor, keys, ent16, out_item, out_user);
        reduce_bf16_kernel<<<(N_ENT * 64) / 256, 256, 0, stream>>>(
            ent16, weight, cursor, keys, out_ent);
    } else if (ws_size >= need_fc) {
        unsigned* cursor = (unsigned*)d_ws;
        unsigned* keys   = cursor + N_ENT;

        (void)hipMemsetAsync(cursor, 0, (size_t)N_ENT * 4, stream);
        scatter_gemm_kernel<<<SCAT_BLKS, 256, 0, stream>>>(
            edge_index, edge_type, entity_emb, aspect_emb, ia_mat, ua_mat,
            cursor, keys, nullptr, out_item, out_user);
        reduce_kernel<<<(N_ENT / 2) * 64 / 256, 256, 0, stream>>>(
            entity_emb, weight, cursor, keys, out_ent);
    } else {
        float* cnt = (float*)d_ws;
        (void)hipMemsetAsync(out_ent, 0, (size_t)N_ENT * CH * sizeof(float), stream);
        (void)hipMemsetAsync(cnt, 0, (size_t)N_ENT * sizeof(float), stream);
        scatter_kernel<<<(N_EDGES * 16 + 255) / 256, 256, 0, stream>>>(
            entity_emb, edge_index, edge_type, weight, out_ent, cnt);
        divide_kernel<<<(N_ENT * 16 + 255) / 256, 256, 0, stream>>>(out_ent, cnt);
        gemm_fallback_kernel<<<TOT_TILES, 256, 0, stream>>>(
            ia_mat, ua_mat, aspect_emb, out_item, out_user);
    }
}